// Round 10
// baseline (73.692 us; speedup 1.0000x reference)
//
#include <hip/hip_runtime.h>
#include <stdint.h>

#define B_N   32
#define T_N   8192
#define D_N   256
#define CTX_N 128
#define TB    32                      /* rows per chunk           */
#define CPB   8                       /* chunks per block         */
#define ROWS_PB (TB*CPB)              /* 256 rows per block       */
#define BLK_PER_B (T_N/ROWS_PB)       /* 32 blocks per batch      */
#define NBLOCKS (B_N*BLK_PER_B)       /* 1024                     */
#define XP    264                     /* bf16 pitch (528 B rows)  */
#define SPW   4                       /* s_part row width (floats), 16B */

typedef unsigned short u16;
typedef unsigned int   u32;
typedef __attribute__((ext_vector_type(8))) short bf16x8;
typedef __attribute__((ext_vector_type(8))) unsigned short u16x8;
typedef __attribute__((ext_vector_type(4))) unsigned short u16x4;
typedef __attribute__((ext_vector_type(4))) float f32x4;

__device__ __forceinline__ u16 f2bf(float f) {          /* RNE float->bf16 */
  u32 u = __float_as_uint(f);
  return (u16)((u + 0x7FFFu + ((u >> 16) & 1u)) >> 16);
}
__device__ __forceinline__ float bf2f(u16 h) {
  return __uint_as_float(((u32)h) << 16);
}
__device__ __forceinline__ float fast_tanh(float x) {
  float e = __expf(2.0f * x);
  return (e - 1.0f) * __builtin_amdgcn_rcpf(e + 1.0f);
}
/* 16-lane rotate-reduce on the VALU (DPP row_ror) — off the DS pipe. */
__device__ __forceinline__ float rr16_add(float v) {
  int x;
  x = __builtin_amdgcn_update_dpp(0, __float_as_int(v), 0x128, 0xF, 0xF, true); v += __int_as_float(x);
  x = __builtin_amdgcn_update_dpp(0, __float_as_int(v), 0x124, 0xF, 0xF, true); v += __int_as_float(x);
  x = __builtin_amdgcn_update_dpp(0, __float_as_int(v), 0x122, 0xF, 0xF, true); v += __int_as_float(x);
  x = __builtin_amdgcn_update_dpp(0, __float_as_int(v), 0x121, 0xF, 0xF, true); v += __int_as_float(x);
  return v;
}

/* ---------- kernel 0: W (D x CTX fp32) -> Wt (CTX x D bf16) ---------- */
__global__ void prep_w(const float* __restrict__ W, u16* __restrict__ Wt) {
  int c = blockIdx.x;    /* ctx */
  int d = threadIdx.x;   /* dim */
  Wt[c * D_N + d] = f2bf(W[d * CTX_N + c]);
}

/* ---------- kernel 1: fused scores+softmax+wsum ----------
   4 waves x 32 ctx cols each (A-redundancy 4x, was 8x). 256 thr,
   launch_bounds(256,3): 12 waves/CU, VGPR cap ~170 -> bw=64 VGPR fits.
   Round-9 pipeline: triple-buffer Xl, one barrier/chunk, deferred wsum. */
__global__ __launch_bounds__(256, 3)
void attn_main(const float* __restrict__ X, const u16* __restrict__ Wt,
               const float* __restrict__ u,
               float* __restrict__ blk_o, float* __restrict__ blk_l) {
  __shared__ u16   Xl[3][TB][XP];                    /* 50688 B triple-buffer */
  __shared__ __align__(16) float s_part[2][TB][SPW]; /* 1024 B, parity       */
  __shared__ float l_part[8];

  const int tid = threadIdx.x;
  const int w   = tid >> 6;           /* wave 0..3: ctx cols w*32..+31 */
  const int l   = tid & 63;
  const int l15 = l & 15;
  const int lg  = l >> 4;

  const int blk  = blockIdx.x;
  const int b    = blk >> 5;                          /* / BLK_PER_B */
  const int rowB = (blk & (BLK_PER_B - 1)) * ROWS_PB;
  const float* Xbase = X + ((size_t)b * T_N + rowB) * D_N;

  /* ---- W^T fragments in registers: 2 ctx-16 tiles x 8 kk = 64 VGPRs ---- */
  bf16x8 bw0[8], bw1[8];
  {
    const u16* wp0 = Wt + (w * 32 + l15) * D_N + lg * 8;
    const u16* wp1 = wp0 + 16 * D_N;
    #pragma unroll
    for (int kk = 0; kk < 8; ++kk) {
      bw0[kk] = *(const bf16x8*)(wp0 + kk * 32);
      bw1[kk] = *(const bf16x8*)(wp1 + kk * 32);
    }
  }
  const float uc0 = u[w * 32 + l15];
  const float uc1 = u[w * 32 + 16 + l15];

  /* staging: load j covers row 4j+w, lane l covers floats l*4..+4 (1KB/instr) */
  const float* Xs = Xbase + (size_t)w * D_N + (l << 2);

  float4 pf0, pf1, pf2, pf3, pf4, pf5, pf6, pf7;
#define LOADP(cn) {                                                      \
    const float* sp_ = Xs + (size_t)(cn) * TB * D_N;                     \
    pf0 = *(const float4*)(sp_ + 0  * D_N * 4);                          \
    pf1 = *(const float4*)(sp_ + 1  * D_N * 4);                          \
    pf2 = *(const float4*)(sp_ + 2  * D_N * 4);                          \
    pf3 = *(const float4*)(sp_ + 3  * D_N * 4);                          \
    pf4 = *(const float4*)(sp_ + 4  * D_N * 4);                          \
    pf5 = *(const float4*)(sp_ + 5  * D_N * 4);                          \
    pf6 = *(const float4*)(sp_ + 6  * D_N * 4);                          \
    pf7 = *(const float4*)(sp_ + 7  * D_N * 4);                          \
  }
#define ST1(P, j) { u16x4 t_;                                            \
    t_[0]=f2bf(P.x); t_[1]=f2bf(P.y); t_[2]=f2bf(P.z); t_[3]=f2bf(P.w);  \
    *(u16x4*)&Xl[cb][4*(j) + w][l << 2] = t_; }

  LOADP(0);

  /* wsum map: thread = (row-quad g, d8 slice) */
  const int g  = tid >> 5;            /* 0..7 -> rows 4g..4g+3 */
  const int sl = tid & 31;            /* d = sl*8 .. +8        */
  float o8[8] = {0,0,0,0,0,0,0,0};
  float l_run = 0.f;

  /* deferred weighted-sum for chunk m (reads s_part[m&1], Xl[m%3]) */
  auto wsum = [&](int m) {
    const int pb = m % 3, sp = m & 1;
    #pragma unroll
    for (int k = 0; k < 4; ++k) {
      const int row = 4 * g + k;
      float4 sa = *(const float4*)&s_part[sp][row][0];
      float st = sa.x; st += sa.y; st += sa.z; st += sa.w;
      float p = __expf(st);            /* |s| <= 6.4 bounded, no max */
      if (sl == 0) l_run += p;
      u16x8 x = *(const u16x8*)&Xl[pb][row][sl * 8];
      #pragma unroll
      for (int j = 0; j < 8; ++j) o8[j] += p * bf2f(x[j]);
    }
  };

  for (int c = 0; c < CPB; ++c) {
    const int cb = c % 3;

    /* ---- stage chunk c (fp32 regs -> bf16 LDS buf[c%3]) ---- */
    ST1(pf0, 0) ST1(pf1, 1) ST1(pf2, 2) ST1(pf3, 3)
    ST1(pf4, 4) ST1(pf5, 5) ST1(pf6, 6) ST1(pf7, 7)

    /* ---- issue next chunk's global loads (fly across the barrier) ---- */
    if (c + 1 < CPB) LOADP(c + 1);

    asm volatile("s_waitcnt lgkmcnt(0)" ::: "memory");
    __builtin_amdgcn_s_barrier();     /* buf[c%3] + s_part[(c-1)&1] ready */
    asm volatile("" ::: "memory");

    /* ---- deferred wsum for chunk c-1 (overlaps MFMA region) ---- */
    if (c >= 1) wsum(c - 1);

    /* ---- scores chunk c: 32 rows x (this wave's 32 ctx cols), K=256 ---- */
    const u16* Xc = &Xl[cb][0][0];
    f32x4 a00 = {0,0,0,0}, a01 = {0,0,0,0}, a10 = {0,0,0,0}, a11 = {0,0,0,0};
    #pragma unroll
    for (int kk = 0; kk < 8; ++kk) {
      bf16x8 fa0 = *(const bf16x8*)(Xc + l15 * XP + kk * 32 + lg * 8);
      bf16x8 fa1 = *(const bf16x8*)(Xc + (16 + l15) * XP + kk * 32 + lg * 8);
      a00 = __builtin_amdgcn_mfma_f32_16x16x32_bf16(fa0, bw0[kk], a00, 0, 0, 0);
      a01 = __builtin_amdgcn_mfma_f32_16x16x32_bf16(fa0, bw1[kk], a01, 0, 0, 0);
      a10 = __builtin_amdgcn_mfma_f32_16x16x32_bf16(fa1, bw0[kk], a10, 0, 0, 0);
      a11 = __builtin_amdgcn_mfma_f32_16x16x32_bf16(fa1, bw1[kk], a11, 0, 0, 0);
    }
    /* partial s over this wave's 32 cols; DPP 16-lane reduce (VALU pipe) */
    #pragma unroll
    for (int r = 0; r < 4; ++r) {
      float v0 = rr16_add(uc0 * fast_tanh(a00[r]) + uc1 * fast_tanh(a01[r]));
      float v1 = rr16_add(uc0 * fast_tanh(a10[r]) + uc1 * fast_tanh(a11[r]));
      if (l15 == 0) {
        s_part[c & 1][lg * 4 + r][w]      = v0;
        s_part[c & 1][16 + lg * 4 + r][w] = v1;
      }
    }
  }

  /* ---- final deferred wsum (chunk CPB-1) ---- */
  asm volatile("s_waitcnt lgkmcnt(0)" ::: "memory");
  __builtin_amdgcn_s_barrier();
  asm volatile("" ::: "memory");
  wsum(CPB - 1);

  /* ---- block combine: 8 row-quad groups -> one partial per d ---- */
  float* comb = (float*)&Xl[0][0][0];   /* 8 KiB, overlays buffer 0 */
  *(float4*)&comb[g * 256 + sl * 8]     = *(float4*)&o8[0];
  *(float4*)&comb[g * 256 + sl * 8 + 4] = *(float4*)&o8[4];
  if (sl == 0) l_part[g] = l_run;
  asm volatile("s_waitcnt lgkmcnt(0)" ::: "memory");
  __builtin_amdgcn_s_barrier();
  asm volatile("" ::: "memory");
  {
    float o = 0.f;
    #pragma unroll
    for (int g2 = 0; g2 < 8; ++g2) o += comb[g2 * 256 + tid];
    blk_o[(size_t)blk * D_N + tid] = o;
  }
  if (tid == 0) {
    float L = 0.f;
    #pragma unroll
    for (int g2 = 0; g2 < 8; ++g2) L += l_part[g2];
    blk_l[blk] = L;
  }
#undef LOADP
#undef ST1
}

/* ---------- kernel 2: combine block-partials per batch ---------- */
__global__ __launch_bounds__(256)
void finalize(const float* __restrict__ blk_o, const float* __restrict__ blk_l,
              float* __restrict__ out) {
  const int b = blockIdx.x, d = threadIdx.x;
  float o = 0.f, L = 0.f;
  for (int i = 0; i < BLK_PER_B; ++i) {
    o += blk_o[(size_t)(b * BLK_PER_B + i) * D_N + d];
    L += blk_l[b * BLK_PER_B + i];
  }
  out[b * D_N + d] = o / L;
}

/* ---------- launch ---------- */
extern "C" void kernel_launch(void* const* d_in, const int* in_sizes, int n_in,
                              void* d_out, int out_size, void* d_ws, size_t ws_size,
                              hipStream_t stream) {
  const float* X = (const float*)d_in[0];
  const float* W = (const float*)d_in[1];
  const float* u = (const float*)d_in[2];
  float* out = (float*)d_out;

  u16*   Wt    = (u16*)d_ws;                                        /* 64 KiB */
  float* blk_o = (float*)((char*)d_ws + 65536);                     /* 1 MiB  */
  float* blk_l = (float*)((char*)d_ws + 65536 + (size_t)NBLOCKS * D_N * 4);

  prep_w<<<CTX_N, D_N, 0, stream>>>(W, Wt);
  attn_main<<<NBLOCKS, 256, 0, stream>>>(X, Wt, u, blk_o, blk_l);
  finalize<<<B_N, 256, 0, stream>>>(blk_o, blk_l, out);
}

// Round 11
// 61.441 us; speedup vs baseline: 1.1994x; 1.1994x over previous
//
#include <hip/hip_runtime.h>
#include <stdint.h>

#define B_N   32
#define T_N   8192
#define D_N   256
#define CTX_N 128
#define TB    32                      /* rows per chunk           */
#define CPB   8                       /* chunks per block         */
#define ROWS_PB (TB*CPB)              /* 256 rows per block       */
#define BLK_PER_B (T_N/ROWS_PB)       /* 32 blocks per batch      */
#define NBLOCKS (B_N*BLK_PER_B)       /* 1024                     */
#define XP    264                     /* bf16 pitch (528 B rows)  */
#define SPW   4                       /* s_part row width (floats) */

typedef unsigned short u16;
typedef unsigned int   u32;
typedef __attribute__((ext_vector_type(8))) short bf16x8;
typedef __attribute__((ext_vector_type(8))) unsigned short u16x8;
typedef __attribute__((ext_vector_type(4))) float f32x4;

__device__ __forceinline__ u16 f2bf(float f) {          /* RNE float->bf16 */
  u32 u = __float_as_uint(f);
  return (u16)((u + 0x7FFFu + ((u >> 16) & 1u)) >> 16);
}
__device__ __forceinline__ float bf2f(u16 h) {
  return __uint_as_float(((u32)h) << 16);
}
__device__ __forceinline__ float fast_tanh(float x) {
  float e = __expf(2.0f * x);
  return (e - 1.0f) * __builtin_amdgcn_rcpf(e + 1.0f);
}
/* 16-lane rotate-reduce on the VALU (DPP row_ror) — off the DS pipe. */
__device__ __forceinline__ float rr16_add(float v) {
  int x;
  x = __builtin_amdgcn_update_dpp(0, __float_as_int(v), 0x128, 0xF, 0xF, true); v += __int_as_float(x);
  x = __builtin_amdgcn_update_dpp(0, __float_as_int(v), 0x124, 0xF, 0xF, true); v += __int_as_float(x);
  x = __builtin_amdgcn_update_dpp(0, __float_as_int(v), 0x122, 0xF, 0xF, true); v += __int_as_float(x);
  x = __builtin_amdgcn_update_dpp(0, __float_as_int(v), 0x121, 0xF, 0xF, true); v += __int_as_float(x);
  return v;
}

/* ---------- kernel 0: W (D x CTX fp32) -> Wt (CTX x D bf16) ---------- */
__global__ void prep_w(const float* __restrict__ W, u16* __restrict__ Wt) {
  int c = blockIdx.x;    /* ctx */
  int d = threadIdx.x;   /* dim */
  Wt[c * D_N + d] = f2bf(W[d * CTX_N + c]);
}

/* ---------- kernel 1: role-split fused attention ----------
   waves 0-3: MFMA, 32 ctx cols each (A-read amplification 4x, was 8x).
   waves 4-7: softmax+wsum, 8 rows each.  All 8 waves stage 64B/thread.
   Round-9 pipeline: triple-buffer Xl, ONE barrier/chunk, wsum deferred. */
__global__ __launch_bounds__(512, 4)
void attn_main(const float* __restrict__ X, const u16* __restrict__ Wt,
               const float* __restrict__ u,
               float* __restrict__ blk_o, float* __restrict__ blk_l) {
  __shared__ u16   Xl[3][TB][XP];                    /* 50688 B triple-buffer */
  __shared__ __align__(16) float s_part[2][TB][SPW]; /* 1024 B, parity       */
  __shared__ float l_part[8];

  const int tid = threadIdx.x;
  const int w   = tid >> 6;           /* wave 0..7 */
  const int l   = tid & 63;
  const int l15 = l & 15;
  const int lg  = l >> 4;

  const int blk  = blockIdx.x;
  const int b    = blk >> 5;                          /* / BLK_PER_B */
  const int rowB = (blk & (BLK_PER_B - 1)) * ROWS_PB;
  const float* Xbase = X + ((size_t)b * T_N + rowB) * D_N;

  /* ---- role A (waves 0-3): W^T frags, 32 ctx cols = 64 VGPRs ---- */
  bf16x8 bw0[8], bw1[8];
  float uc0 = 0.f, uc1 = 0.f;
  if (w < 4) {
    const u16* wp0 = Wt + (w * 32 + l15) * D_N + lg * 8;
    const u16* wp1 = wp0 + 16 * D_N;
    #pragma unroll
    for (int kk = 0; kk < 8; ++kk) {
      bw0[kk] = *(const bf16x8*)(wp0 + kk * 32);
      bw1[kk] = *(const bf16x8*)(wp1 + kk * 32);
    }
    uc0 = u[w * 32 + l15];
    uc1 = u[w * 32 + 16 + l15];
  }

  /* ---- staging map (ALL waves): row srow, 16-float segment scol ---- */
  const int srow = tid >> 4;          /* 0..31 */
  const int scol = (tid & 15) << 4;   /* 0,16,...,240 */
  const float* Xrow = Xbase + (size_t)srow * D_N + scol;

  float4 pf0, pf1, pf2, pf3;          /* prefetch regs (16 VGPRs) */
  pf0 = ((const float4*)Xrow)[0]; pf1 = ((const float4*)Xrow)[1];
  pf2 = ((const float4*)Xrow)[2]; pf3 = ((const float4*)Xrow)[3];

  /* ---- role B (waves 4-7): wsum map, 8 rows per wave ---- */
  const int hw   = w - 4;             /* 0..3 (valid when w>=4) */
  const int subr = l >> 5;            /* 0/1 */
  const int sl   = l & 31;            /* d = sl*8 .. +8 */
  float o8[8] = {0,0,0,0,0,0,0,0};
  float l_run = 0.f;

  /* deferred softmax+wsum for chunk m (waves 4-7 only) */
  auto wsum = [&](int m) {
    const int pb = m % 3, sp = m & 1;
    #pragma unroll
    for (int k = 0; k < 4; ++k) {
      const int row = hw * 8 + 2 * k + subr;
      float4 sa = *(const float4*)&s_part[sp][row][0];
      float st = sa.x; st += sa.y; st += sa.z; st += sa.w;
      float p = __expf(st);            /* |s| <= 6.4 bounded, no max */
      if (sl == 0) l_run += p;
      u16x8 x = *(const u16x8*)&Xl[pb][row][sl * 8];
      #pragma unroll
      for (int j = 0; j < 8; ++j) o8[j] += p * bf2f(x[j]);
    }
  };

  for (int c = 0; c < CPB; ++c) {
    const int cb = c % 3;

    /* ---- stage chunk c (ALL waves, fp32 regs -> bf16 LDS buf[c%3]) ---- */
    u16x8 s0, s1;
    s0[0]=f2bf(pf0.x); s0[1]=f2bf(pf0.y); s0[2]=f2bf(pf0.z); s0[3]=f2bf(pf0.w);
    s0[4]=f2bf(pf1.x); s0[5]=f2bf(pf1.y); s0[6]=f2bf(pf1.z); s0[7]=f2bf(pf1.w);
    s1[0]=f2bf(pf2.x); s1[1]=f2bf(pf2.y); s1[2]=f2bf(pf2.z); s1[3]=f2bf(pf2.w);
    s1[4]=f2bf(pf3.x); s1[5]=f2bf(pf3.y); s1[6]=f2bf(pf3.z); s1[7]=f2bf(pf3.w);
    *(u16x8*)&Xl[cb][srow][scol]     = s0;
    *(u16x8*)&Xl[cb][srow][scol + 8] = s1;

    /* ---- issue next chunk's global loads (fly across the barrier) ---- */
    if (c + 1 < CPB) {
      const float* sp_ = Xrow + (size_t)(c + 1) * TB * D_N;
      pf0 = ((const float4*)sp_)[0]; pf1 = ((const float4*)sp_)[1];
      pf2 = ((const float4*)sp_)[2]; pf3 = ((const float4*)sp_)[3];
    }

    asm volatile("s_waitcnt lgkmcnt(0)" ::: "memory");
    __builtin_amdgcn_s_barrier();     /* buf[c%3] + s_part[(c-1)&1] ready */
    asm volatile("" ::: "memory");

    if (w < 4) {
      /* ---- scores chunk c: 32 rows x 32 ctx, two 16-row tiles ---- */
      const u16* Xc = &Xl[cb][0][0];
      #pragma unroll
      for (int t = 0; t < 2; ++t) {
        f32x4 acc0 = {0,0,0,0}, acc1 = {0,0,0,0};
        #pragma unroll
        for (int kk = 0; kk < 8; ++kk) {
          bf16x8 a = *(const bf16x8*)(Xc + (t * 16 + l15) * XP + kk * 32 + lg * 8);
          acc0 = __builtin_amdgcn_mfma_f32_16x16x32_bf16(a, bw0[kk], acc0, 0, 0, 0);
          acc1 = __builtin_amdgcn_mfma_f32_16x16x32_bf16(a, bw1[kk], acc1, 0, 0, 0);
        }
        #pragma unroll
        for (int r = 0; r < 4; ++r) {
          float v = rr16_add(uc0 * fast_tanh(acc0[r]) + uc1 * fast_tanh(acc1[r]));
          if (l15 == 0) s_part[c & 1][t * 16 + lg * 4 + r][w] = v;
        }
      }
    } else {
      /* ---- deferred softmax+wsum for chunk c-1 ---- */
      if (c >= 1) wsum(c - 1);
    }
  }

  /* ---- tail: last chunk's wsum needs MFMA(CPB-1)'s s_part ---- */
  asm volatile("s_waitcnt lgkmcnt(0)" ::: "memory");
  __builtin_amdgcn_s_barrier();
  asm volatile("" ::: "memory");
  float* comb = (float*)&Xl[0][0][0];   /* 8 KiB overlay on buffer 0 */
  if (w >= 4) {
    wsum(CPB - 1);                      /* reads buf[(CPB-1)%3]=buf1, safe */
    const int q = hw * 2 + subr;        /* 0..7 partial sets */
    *(float4*)&comb[q * 256 + sl * 8]     = *(float4*)&o8[0];
    *(float4*)&comb[q * 256 + sl * 8 + 4] = *(float4*)&o8[4];
    if (sl == 0) l_part[q] = l_run;
  }
  asm volatile("s_waitcnt lgkmcnt(0)" ::: "memory");
  __builtin_amdgcn_s_barrier();
  asm volatile("" ::: "memory");
  if (tid < 256) {
    float o = 0.f;
    #pragma unroll
    for (int q2 = 0; q2 < 8; ++q2) o += comb[q2 * 256 + tid];
    blk_o[(size_t)blk * D_N + tid] = o;
  }
  if (tid == 0) {
    float L = 0.f;
    #pragma unroll
    for (int q2 = 0; q2 < 8; ++q2) L += l_part[q2];
    blk_l[blk] = L;
  }
}

/* ---------- kernel 2: combine block-partials per batch ---------- */
__global__ __launch_bounds__(256)
void finalize(const float* __restrict__ blk_o, const float* __restrict__ blk_l,
              float* __restrict__ out) {
  const int b = blockIdx.x, d = threadIdx.x;
  float o = 0.f, L = 0.f;
  for (int i = 0; i < BLK_PER_B; ++i) {
    o += blk_o[(size_t)(b * BLK_PER_B + i) * D_N + d];
    L += blk_l[b * BLK_PER_B + i];
  }
  out[b * D_N + d] = o / L;
}

/* ---------- launch ---------- */
extern "C" void kernel_launch(void* const* d_in, const int* in_sizes, int n_in,
                              void* d_out, int out_size, void* d_ws, size_t ws_size,
                              hipStream_t stream) {
  const float* X = (const float*)d_in[0];
  const float* W = (const float*)d_in[1];
  const float* u = (const float*)d_in[2];
  float* out = (float*)d_out;

  u16*   Wt    = (u16*)d_ws;                                        /* 64 KiB */
  float* blk_o = (float*)((char*)d_ws + 65536);                     /* 1 MiB  */
  float* blk_l = (float*)((char*)d_ws + 65536 + (size_t)NBLOCKS * D_N * 4);

  prep_w<<<CTX_N, D_N, 0, stream>>>(W, Wt);
  attn_main<<<NBLOCKS, 512, 0, stream>>>(X, Wt, u, blk_o, blk_l);
  finalize<<<B_N, 256, 0, stream>>>(blk_o, blk_l, out);
}

// Round 12
// 60.086 us; speedup vs baseline: 1.2264x; 1.0226x over previous
//
#include <hip/hip_runtime.h>
#include <stdint.h>

#define B_N   32
#define T_N   8192
#define D_N   256
#define CTX_N 128
#define TB    32                      /* rows per chunk           */
#define CPB   8                       /* chunks per block         */
#define ROWS_PB (TB*CPB)              /* 256 rows per block       */
#define BLK_PER_B (T_N/ROWS_PB)       /* 32 blocks per batch      */
#define NBLOCKS (B_N*BLK_PER_B)       /* 1024                     */
#define XP    264                     /* bf16 pitch (528 B rows)  */
#define SPW   12                      /* s_part row width (floats), 48B */

typedef unsigned short u16;
typedef unsigned int   u32;
typedef __attribute__((ext_vector_type(8))) short bf16x8;
typedef __attribute__((ext_vector_type(8))) unsigned short u16x8;
typedef __attribute__((ext_vector_type(4))) float f32x4;

__device__ __forceinline__ u16 f2bf(float f) {          /* RNE float->bf16 */
  u32 u = __float_as_uint(f);
  return (u16)((u + 0x7FFFu + ((u >> 16) & 1u)) >> 16);
}
__device__ __forceinline__ float bf2f(u16 h) {
  return __uint_as_float(((u32)h) << 16);
}
__device__ __forceinline__ float fast_tanh(float x) {
  float e = __expf(2.0f * x);
  return (e - 1.0f) * __builtin_amdgcn_rcpf(e + 1.0f);
}
/* 16-lane rotate-reduce on the VALU (DPP row_ror) — off the DS pipe. */
__device__ __forceinline__ float rr16_add(float v) {
  int x;
  x = __builtin_amdgcn_update_dpp(0, __float_as_int(v), 0x128, 0xF, 0xF, true); v += __int_as_float(x);
  x = __builtin_amdgcn_update_dpp(0, __float_as_int(v), 0x124, 0xF, 0xF, true); v += __int_as_float(x);
  x = __builtin_amdgcn_update_dpp(0, __float_as_int(v), 0x122, 0xF, 0xF, true); v += __int_as_float(x);
  x = __builtin_amdgcn_update_dpp(0, __float_as_int(v), 0x121, 0xF, 0xF, true); v += __int_as_float(x);
  return v;
}

/* ---------- kernel 0: W (D x CTX fp32) -> Wt (CTX x D bf16) ---------- */
__global__ void prep_w(const float* __restrict__ W, u16* __restrict__ Wt) {
  int c = blockIdx.x;    /* ctx */
  int d = threadIdx.x;   /* dim */
  Wt[c * D_N + d] = f2bf(W[d * CTX_N + c]);
}

/* ---------- kernel 1: fused scores+softmax+wsum ----------
   Round-9 pipeline (triple-buffer Xl, ONE barrier/chunk, deferred wsum)
   + wave-parity phase stagger: even waves MFMA-then-wsum, odd waves
   wsum-then-MFMA, to decorrelate DS-pipe bursts across the block. */
__global__ __launch_bounds__(512, 4)
void attn_main(const float* __restrict__ X, const u16* __restrict__ Wt,
               const float* __restrict__ u,
               float* __restrict__ blk_o, float* __restrict__ blk_l) {
  __shared__ u16   Xl[3][TB][XP];                    /* 50688 B triple-buffer */
  __shared__ __align__(16) float s_part[2][TB][SPW]; /* 3072 B, parity       */
  __shared__ float l_part[16];

  const int tid = threadIdx.x;
  const int w   = tid >> 6;           /* wave 0..7: owns ctx cols w*16..+15 */
  const int l   = tid & 63;
  const int l15 = l & 15;
  const int lg  = l >> 4;

  const int blk  = blockIdx.x;
  const int b    = blk >> 5;                          /* / BLK_PER_B */
  const int rowB = (blk & (BLK_PER_B - 1)) * ROWS_PB;
  const float* Xbase = X + ((size_t)b * T_N + rowB) * D_N;

  /* ---- W^T fragments in registers: 8 x bf16x8 = 32 VGPRs ---- */
  bf16x8 bw[8];
  {
    const u16* wp = Wt + (w * 16 + l15) * D_N + lg * 8;
    #pragma unroll
    for (int kk = 0; kk < 8; ++kk) bw[kk] = *(const bf16x8*)(wp + kk * 32);
  }
  const float uc = u[w * 16 + l15];

  /* staging map: thread = (row srow, 16-float segment scol) */
  const int srow = tid >> 4;          /* 0..31 */
  const int scol = (tid & 15) << 4;   /* 0,16,...,240 */
  const float* Xrow = Xbase + (size_t)srow * D_N + scol;

  float4 pf0, pf1, pf2, pf3;          /* prefetch regs (next chunk) */
  pf0 = ((const float4*)Xrow)[0]; pf1 = ((const float4*)Xrow)[1];
  pf2 = ((const float4*)Xrow)[2]; pf3 = ((const float4*)Xrow)[3];

  /* wsum map: thread = (t-pair g, d8 slice) */
  const int g     = tid >> 5;         /* 0..15 -> rows 2g,2g+1 */
  const int slice = tid & 31;         /* d = slice*8 .. +8     */
  float o8[8] = {0,0,0,0,0,0,0,0};
  float l_run = 0.f;

  /* deferred weighted-sum for chunk m (reads s_part[m&1], Xl[m%3]) */
  auto wsum = [&](int m) {
    const int pb = m % 3, sp = m & 1;
    float4 sa0 = *(const float4*)&s_part[sp][2 * g][0];
    float4 sa1 = *(const float4*)&s_part[sp][2 * g][4];
    float4 sb0 = *(const float4*)&s_part[sp][2 * g + 1][0];
    float4 sb1 = *(const float4*)&s_part[sp][2 * g + 1][4];
    float st0 = sa0.x; st0 += sa0.y; st0 += sa0.z; st0 += sa0.w;
    st0 += sa1.x; st0 += sa1.y; st0 += sa1.z; st0 += sa1.w;
    float st1 = sb0.x; st1 += sb0.y; st1 += sb0.z; st1 += sb0.w;
    st1 += sb1.x; st1 += sb1.y; st1 += sb1.z; st1 += sb1.w;
    float p0 = __expf(st0), p1 = __expf(st1);
    if (slice == 0) l_run += p0 + p1;
    u16x8 x0 = *(const u16x8*)&Xl[pb][2 * g][slice * 8];
    u16x8 x1 = *(const u16x8*)&Xl[pb][2 * g + 1][slice * 8];
    #pragma unroll
    for (int j = 0; j < 8; ++j) o8[j] += p0 * bf2f(x0[j]) + p1 * bf2f(x1[j]);
  };

  /* MFMA + tanh + u-dot + DPP reduce for chunk c into s_part[c&1] */
  auto scores = [&](int c, int cb) {
    const u16* Xc = &Xl[cb][0][0];
    f32x4 acc0 = {0,0,0,0}, acc1 = {0,0,0,0};
    #pragma unroll
    for (int kk = 0; kk < 8; ++kk) {
      bf16x8 a0 = *(const bf16x8*)(Xc + l15 * XP + kk * 32 + lg * 8);
      bf16x8 a1 = *(const bf16x8*)(Xc + (16 + l15) * XP + kk * 32 + lg * 8);
      acc0 = __builtin_amdgcn_mfma_f32_16x16x32_bf16(a0, bw[kk], acc0, 0, 0, 0);
      acc1 = __builtin_amdgcn_mfma_f32_16x16x32_bf16(a1, bw[kk], acc1, 0, 0, 0);
    }
    #pragma unroll
    for (int r = 0; r < 4; ++r) {
      float v0 = rr16_add(uc * fast_tanh(acc0[r]));
      float v1 = rr16_add(uc * fast_tanh(acc1[r]));
      if (l15 == 0) {
        s_part[c & 1][lg * 4 + r][w]      = v0;
        s_part[c & 1][16 + lg * 4 + r][w] = v1;
      }
    }
  };

  for (int c = 0; c < CPB; ++c) {
    const int cb = c % 3;

    /* ---- stage chunk c (fp32 regs -> bf16 LDS buf[c%3]) ---- */
    u16x8 s0, s1;
    s0[0]=f2bf(pf0.x); s0[1]=f2bf(pf0.y); s0[2]=f2bf(pf0.z); s0[3]=f2bf(pf0.w);
    s0[4]=f2bf(pf1.x); s0[5]=f2bf(pf1.y); s0[6]=f2bf(pf1.z); s0[7]=f2bf(pf1.w);
    s1[0]=f2bf(pf2.x); s1[1]=f2bf(pf2.y); s1[2]=f2bf(pf2.z); s1[3]=f2bf(pf2.w);
    s1[4]=f2bf(pf3.x); s1[5]=f2bf(pf3.y); s1[6]=f2bf(pf3.z); s1[7]=f2bf(pf3.w);
    *(u16x8*)&Xl[cb][srow][scol]     = s0;
    *(u16x8*)&Xl[cb][srow][scol + 8] = s1;

    /* ---- issue next chunk's global loads (fly across the barrier) ---- */
    if (c + 1 < CPB) {
      const float* sp_ = Xrow + (size_t)(c + 1) * TB * D_N;
      pf0 = ((const float4*)sp_)[0]; pf1 = ((const float4*)sp_)[1];
      pf2 = ((const float4*)sp_)[2]; pf3 = ((const float4*)sp_)[3];
    }

    asm volatile("s_waitcnt lgkmcnt(0)" ::: "memory");
    __builtin_amdgcn_s_barrier();     /* buf[c%3] + s_part[(c-1)&1] ready */
    asm volatile("" ::: "memory");

    /* ---- phase-staggered region: both orders are valid (disjoint bufs) ---- */
    if (w & 1) {
      if (c >= 1) wsum(c - 1);
      scores(c, cb);
    } else {
      scores(c, cb);
      if (c >= 1) wsum(c - 1);
    }
  }

  /* ---- final deferred wsum (chunk CPB-1) ---- */
  asm volatile("s_waitcnt lgkmcnt(0)" ::: "memory");
  __builtin_amdgcn_s_barrier();
  asm volatile("" ::: "memory");
  wsum(CPB - 1);

  /* ---- block combine: 16 t-groups -> one partial per d ---- */
  asm volatile("s_waitcnt lgkmcnt(0)" ::: "memory");
  __builtin_amdgcn_s_barrier();
  asm volatile("" ::: "memory");
  float* comb = (float*)&Xl[0][0][0];   /* 16 KiB, overlays buffer 0 */
  #pragma unroll
  for (int j = 0; j < 8; ++j) comb[g * 256 + slice * 8 + j] = o8[j];
  if (slice == 0) l_part[g] = l_run;
  asm volatile("s_waitcnt lgkmcnt(0)" ::: "memory");
  __builtin_amdgcn_s_barrier();
  asm volatile("" ::: "memory");
  if (tid < 256) {
    float o = 0.f;
    #pragma unroll
    for (int g2 = 0; g2 < 16; ++g2) o += comb[g2 * 256 + tid];
    blk_o[(size_t)blk * D_N + tid] = o;
  }
  if (tid == 0) {
    float L = 0.f;
    #pragma unroll
    for (int g2 = 0; g2 < 16; ++g2) L += l_part[g2];
    blk_l[blk] = L;
  }
}

/* ---------- kernel 2: combine block-partials per batch ---------- */
__global__ __launch_bounds__(256)
void finalize(const float* __restrict__ blk_o, const float* __restrict__ blk_l,
              float* __restrict__ out) {
  const int b = blockIdx.x, d = threadIdx.x;
  float o = 0.f, L = 0.f;
  for (int i = 0; i < BLK_PER_B; ++i) {
    o += blk_o[(size_t)(b * BLK_PER_B + i) * D_N + d];
    L += blk_l[b * BLK_PER_B + i];
  }
  out[b * D_N + d] = o / L;
}

/* ---------- launch ---------- */
extern "C" void kernel_launch(void* const* d_in, const int* in_sizes, int n_in,
                              void* d_out, int out_size, void* d_ws, size_t ws_size,
                              hipStream_t stream) {
  const float* X = (const float*)d_in[0];
  const float* W = (const float*)d_in[1];
  const float* u = (const float*)d_in[2];
  float* out = (float*)d_out;

  u16*   Wt    = (u16*)d_ws;                                        /* 64 KiB */
  float* blk_o = (float*)((char*)d_ws + 65536);                     /* 1 MiB  */
  float* blk_l = (float*)((char*)d_ws + 65536 + (size_t)NBLOCKS * D_N * 4);

  prep_w<<<CTX_N, D_N, 0, stream>>>(W, Wt);
  attn_main<<<NBLOCKS, 512, 0, stream>>>(X, Wt, u, blk_o, blk_l);
  finalize<<<B_N, 256, 0, stream>>>(blk_o, blk_l, out);
}

// Round 13
// 56.182 us; speedup vs baseline: 1.3117x; 1.0695x over previous
//
#include <hip/hip_runtime.h>
#include <stdint.h>

#define B_N   32
#define T_N   8192
#define D_N   256
#define CTX_N 128
#define TB    32                      /* rows per chunk           */
#define CPB   16                      /* chunks per block         */
#define ROWS_PB (TB*CPB)              /* 512 rows per block       */
#define BLK_PER_B (T_N/ROWS_PB)       /* 16 blocks per batch      */
#define NBLOCKS (B_N*BLK_PER_B)       /* 512 = 2 per CU, all resident */
#define XP    264                     /* bf16 pitch (528 B rows)  */
#define SPW   12                      /* s_part row width (floats), 48B */

typedef unsigned short u16;
typedef unsigned int   u32;
typedef __attribute__((ext_vector_type(8))) short bf16x8;
typedef __attribute__((ext_vector_type(8))) unsigned short u16x8;
typedef __attribute__((ext_vector_type(4))) float f32x4;

__device__ __forceinline__ u16 f2bf(float f) {          /* RNE float->bf16 */
  u32 u = __float_as_uint(f);
  return (u16)((u + 0x7FFFu + ((u >> 16) & 1u)) >> 16);
}
__device__ __forceinline__ float bf2f(u16 h) {
  return __uint_as_float(((u32)h) << 16);
}
__device__ __forceinline__ float fast_tanh(float x) {
  float e = __expf(2.0f * x);
  return (e - 1.0f) * __builtin_amdgcn_rcpf(e + 1.0f);
}
/* 16-lane rotate-reduce on the VALU (DPP row_ror) — off the DS pipe. */
__device__ __forceinline__ float rr16_add(float v) {
  int x;
  x = __builtin_amdgcn_update_dpp(0, __float_as_int(v), 0x128, 0xF, 0xF, true); v += __int_as_float(x);
  x = __builtin_amdgcn_update_dpp(0, __float_as_int(v), 0x124, 0xF, 0xF, true); v += __int_as_float(x);
  x = __builtin_amdgcn_update_dpp(0, __float_as_int(v), 0x122, 0xF, 0xF, true); v += __int_as_float(x);
  x = __builtin_amdgcn_update_dpp(0, __float_as_int(v), 0x121, 0xF, 0xF, true); v += __int_as_float(x);
  return v;
}

/* ---------- kernel 0: W (D x CTX fp32) -> Wt (CTX x D bf16) ---------- */
__global__ void prep_w(const float* __restrict__ W, u16* __restrict__ Wt) {
  int c = blockIdx.x;    /* ctx */
  int d = threadIdx.x;   /* dim */
  Wt[c * D_N + d] = f2bf(W[d * CTX_N + c]);
}

/* ---------- kernel 1: fused scores+softmax+wsum ----------
   Round-9 structure: triple-buffer Xl, ONE barrier/chunk, deferred wsum.
   CPB=16: all 512 blocks resident (2/CU), single prologue per block. */
__global__ __launch_bounds__(512, 4)
void attn_main(const float* __restrict__ X, const u16* __restrict__ Wt,
               const float* __restrict__ u,
               float* __restrict__ blk_o, float* __restrict__ blk_l) {
  __shared__ u16   Xl[3][TB][XP];                    /* 50688 B triple-buffer */
  __shared__ __align__(16) float s_part[2][TB][SPW]; /* 3072 B, parity       */
  __shared__ float l_part[16];

  const int tid = threadIdx.x;
  const int w   = tid >> 6;           /* wave 0..7: owns ctx cols w*16..+15 */
  const int l   = tid & 63;
  const int l15 = l & 15;
  const int lg  = l >> 4;

  const int blk  = blockIdx.x;
  const int b    = blk >> 4;                          /* / BLK_PER_B */
  const int rowB = (blk & (BLK_PER_B - 1)) * ROWS_PB;
  const float* Xbase = X + ((size_t)b * T_N + rowB) * D_N;

  /* ---- W^T fragments in registers: 8 x bf16x8 = 32 VGPRs ---- */
  bf16x8 bw[8];
  {
    const u16* wp = Wt + (w * 16 + l15) * D_N + lg * 8;
    #pragma unroll
    for (int kk = 0; kk < 8; ++kk) bw[kk] = *(const bf16x8*)(wp + kk * 32);
  }
  const float uc = u[w * 16 + l15];

  /* staging map: thread = (row srow, 16-float segment scol) */
  const int srow = tid >> 4;          /* 0..31 */
  const int scol = (tid & 15) << 4;   /* 0,16,...,240 */
  const float* Xrow = Xbase + (size_t)srow * D_N + scol;

  float4 pf0, pf1, pf2, pf3;          /* prefetch regs (next chunk) */
  pf0 = ((const float4*)Xrow)[0]; pf1 = ((const float4*)Xrow)[1];
  pf2 = ((const float4*)Xrow)[2]; pf3 = ((const float4*)Xrow)[3];

  /* wsum map: thread = (t-pair g, d8 slice) */
  const int g     = tid >> 5;         /* 0..15 -> rows 2g,2g+1 */
  const int slice = tid & 31;         /* d = slice*8 .. +8     */
  float o8[8] = {0,0,0,0,0,0,0,0};
  float l_run = 0.f;

  /* deferred weighted-sum for chunk m (reads s_part[m&1], Xl[m%3]) */
  auto wsum = [&](int m) {
    const int pb = m % 3, sp = m & 1;
    float4 sa0 = *(const float4*)&s_part[sp][2 * g][0];
    float4 sa1 = *(const float4*)&s_part[sp][2 * g][4];
    float4 sb0 = *(const float4*)&s_part[sp][2 * g + 1][0];
    float4 sb1 = *(const float4*)&s_part[sp][2 * g + 1][4];
    float st0 = sa0.x; st0 += sa0.y; st0 += sa0.z; st0 += sa0.w;
    st0 += sa1.x; st0 += sa1.y; st0 += sa1.z; st0 += sa1.w;
    float st1 = sb0.x; st1 += sb0.y; st1 += sb0.z; st1 += sb0.w;
    st1 += sb1.x; st1 += sb1.y; st1 += sb1.z; st1 += sb1.w;
    float p0 = __expf(st0), p1 = __expf(st1);
    if (slice == 0) l_run += p0 + p1;
    u16x8 x0 = *(const u16x8*)&Xl[pb][2 * g][slice * 8];
    u16x8 x1 = *(const u16x8*)&Xl[pb][2 * g + 1][slice * 8];
    #pragma unroll
    for (int j = 0; j < 8; ++j) o8[j] += p0 * bf2f(x0[j]) + p1 * bf2f(x1[j]);
  };

  for (int c = 0; c < CPB; ++c) {
    const int cb = c % 3;

    /* ---- stage chunk c (fp32 regs -> bf16 LDS buf[c%3]) ---- */
    u16x8 s0, s1;
    s0[0]=f2bf(pf0.x); s0[1]=f2bf(pf0.y); s0[2]=f2bf(pf0.z); s0[3]=f2bf(pf0.w);
    s0[4]=f2bf(pf1.x); s0[5]=f2bf(pf1.y); s0[6]=f2bf(pf1.z); s0[7]=f2bf(pf1.w);
    s1[0]=f2bf(pf2.x); s1[1]=f2bf(pf2.y); s1[2]=f2bf(pf2.z); s1[3]=f2bf(pf2.w);
    s1[4]=f2bf(pf3.x); s1[5]=f2bf(pf3.y); s1[6]=f2bf(pf3.z); s1[7]=f2bf(pf3.w);
    *(u16x8*)&Xl[cb][srow][scol]     = s0;
    *(u16x8*)&Xl[cb][srow][scol + 8] = s1;

    /* ---- issue next chunk's global loads (fly across the barrier) ---- */
    if (c + 1 < CPB) {
      const float* sp_ = Xrow + (size_t)(c + 1) * TB * D_N;
      pf0 = ((const float4*)sp_)[0]; pf1 = ((const float4*)sp_)[1];
      pf2 = ((const float4*)sp_)[2]; pf3 = ((const float4*)sp_)[3];
    }

    asm volatile("s_waitcnt lgkmcnt(0)" ::: "memory");
    __builtin_amdgcn_s_barrier();     /* buf[c%3] + s_part[(c-1)&1] ready */
    asm volatile("" ::: "memory");

    /* ---- deferred wsum for chunk c-1 (overlaps MFMA region) ---- */
    if (c >= 1) wsum(c - 1);

    /* ---- scores chunk c: 32 rows x (this wave's 16 ctx cols), K=256 ---- */
    const u16* Xc = &Xl[cb][0][0];
    f32x4 acc0 = {0,0,0,0}, acc1 = {0,0,0,0};
    #pragma unroll
    for (int kk = 0; kk < 8; ++kk) {
      bf16x8 a0 = *(const bf16x8*)(Xc + l15 * XP + kk * 32 + lg * 8);
      bf16x8 a1 = *(const bf16x8*)(Xc + (16 + l15) * XP + kk * 32 + lg * 8);
      acc0 = __builtin_amdgcn_mfma_f32_16x16x32_bf16(a0, bw[kk], acc0, 0, 0, 0);
      acc1 = __builtin_amdgcn_mfma_f32_16x16x32_bf16(a1, bw[kk], acc1, 0, 0, 0);
    }
    /* partial s over this wave's cols; DPP 16-lane reduce (VALU pipe) */
    #pragma unroll
    for (int r = 0; r < 4; ++r) {
      float v0 = rr16_add(uc * fast_tanh(acc0[r]));
      float v1 = rr16_add(uc * fast_tanh(acc1[r]));
      if (l15 == 0) {
        s_part[c & 1][lg * 4 + r][w]      = v0;
        s_part[c & 1][16 + lg * 4 + r][w] = v1;
      }
    }
  }

  /* ---- final deferred wsum (chunk CPB-1) ---- */
  asm volatile("s_waitcnt lgkmcnt(0)" ::: "memory");
  __builtin_amdgcn_s_barrier();
  asm volatile("" ::: "memory");
  wsum(CPB - 1);

  /* ---- block combine: 16 t-groups -> one partial per d ---- */
  asm volatile("s_waitcnt lgkmcnt(0)" ::: "memory");
  __builtin_amdgcn_s_barrier();
  asm volatile("" ::: "memory");
  float* comb = (float*)&Xl[0][0][0];   /* 16 KiB, overlays buffer 0 */
  #pragma unroll
  for (int j = 0; j < 8; ++j) comb[g * 256 + slice * 8 + j] = o8[j];
  if (slice == 0) l_part[g] = l_run;
  asm volatile("s_waitcnt lgkmcnt(0)" ::: "memory");
  __builtin_amdgcn_s_barrier();
  asm volatile("" ::: "memory");
  if (tid < 256) {
    float o = 0.f;
    #pragma unroll
    for (int g2 = 0; g2 < 16; ++g2) o += comb[g2 * 256 + tid];
    blk_o[(size_t)blk * D_N + tid] = o;
  }
  if (tid == 0) {
    float L = 0.f;
    #pragma unroll
    for (int g2 = 0; g2 < 16; ++g2) L += l_part[g2];
    blk_l[blk] = L;
  }
}

/* ---------- kernel 2: combine block-partials per batch ---------- */
__global__ __launch_bounds__(256)
void finalize(const float* __restrict__ blk_o, const float* __restrict__ blk_l,
              float* __restrict__ out) {
  const int b = blockIdx.x, d = threadIdx.x;
  float o = 0.f, L = 0.f;
  for (int i = 0; i < BLK_PER_B; ++i) {
    o += blk_o[(size_t)(b * BLK_PER_B + i) * D_N + d];
    L += blk_l[b * BLK_PER_B + i];
  }
  out[b * D_N + d] = o / L;
}

/* ---------- launch ---------- */
extern "C" void kernel_launch(void* const* d_in, const int* in_sizes, int n_in,
                              void* d_out, int out_size, void* d_ws, size_t ws_size,
                              hipStream_t stream) {
  const float* X = (const float*)d_in[0];
  const float* W = (const float*)d_in[1];
  const float* u = (const float*)d_in[2];
  float* out = (float*)d_out;

  u16*   Wt    = (u16*)d_ws;                                        /* 64 KiB */
  float* blk_o = (float*)((char*)d_ws + 65536);                     /* 512 KiB */
  float* blk_l = (float*)((char*)d_ws + 65536 + (size_t)NBLOCKS * D_N * 4);

  prep_w<<<CTX_N, D_N, 0, stream>>>(W, Wt);
  attn_main<<<NBLOCKS, 512, 0, stream>>>(X, Wt, u, blk_o, blk_l);
  finalize<<<B_N, 256, 0, stream>>>(blk_o, blk_l, out);
}

// Round 14
// 55.713 us; speedup vs baseline: 1.3227x; 1.0084x over previous
//
#include <hip/hip_runtime.h>
#include <hip/hip_bf16.h>
#include <stdint.h>

#define B_N   32
#define T_N   8192
#define D_N   256
#define CTX_N 128
#define TB    32                      /* rows per chunk           */
#define CPB   16                      /* chunks per block         */
#define ROWS_PB (TB*CPB)              /* 512 rows per block       */
#define BLK_PER_B (T_N/ROWS_PB)       /* 16 blocks per batch      */
#define NBLOCKS (B_N*BLK_PER_B)       /* 512 = 2 per CU, all resident */
#define XP    264                     /* bf16 pitch (528 B rows)  */
#define SPW   12                      /* s_part row width (floats), 48B */

typedef unsigned short u16;
typedef unsigned int   u32;
typedef __attribute__((ext_vector_type(8))) short bf16x8;
typedef __attribute__((ext_vector_type(8))) unsigned short u16x8;
typedef __attribute__((ext_vector_type(4))) float f32x4;

__device__ __forceinline__ u16 f2bf(float f) {   /* compiler cast (RNE) */
  __hip_bfloat16 h = __float2bfloat16(f);
  return *reinterpret_cast<u16*>(&h);
}
__device__ __forceinline__ float bf2f(u16 h) {
  return __uint_as_float(((u32)h) << 16);
}
__device__ __forceinline__ float fast_tanh(float x) {
  float e = __expf(2.0f * x);
  return (e - 1.0f) * __builtin_amdgcn_rcpf(e + 1.0f);
}
/* 16-lane rotate-reduce on the VALU (DPP row_ror) — off the DS pipe.
   Leaves the full 16-lane sum in EVERY lane of the group. */
__device__ __forceinline__ float rr16_add(float v) {
  int x;
  x = __builtin_amdgcn_update_dpp(0, __float_as_int(v), 0x128, 0xF, 0xF, true); v += __int_as_float(x);
  x = __builtin_amdgcn_update_dpp(0, __float_as_int(v), 0x124, 0xF, 0xF, true); v += __int_as_float(x);
  x = __builtin_amdgcn_update_dpp(0, __float_as_int(v), 0x122, 0xF, 0xF, true); v += __int_as_float(x);
  x = __builtin_amdgcn_update_dpp(0, __float_as_int(v), 0x121, 0xF, 0xF, true); v += __int_as_float(x);
  return v;
}

/* ---------- kernel 0: W (D x CTX fp32) -> Wt (CTX x D bf16) ---------- */
__global__ void prep_w(const float* __restrict__ W, u16* __restrict__ Wt) {
  int c = blockIdx.x;    /* ctx */
  int d = threadIdx.x;   /* dim */
  Wt[c * D_N + d] = f2bf(W[d * CTX_N + c]);
}

/* ---------- kernel 1: fused scores+softmax+wsum ----------
   Round-13 structure (triple-buffer, ONE barrier/chunk, deferred wsum,
   CPB=16 all-resident) + packed s_part writes (8->2 ds_write/wave)
   + compiler bf16 casts. */
__global__ __launch_bounds__(512, 4)
void attn_main(const float* __restrict__ X, const u16* __restrict__ Wt,
               const float* __restrict__ u,
               float* __restrict__ blk_o, float* __restrict__ blk_l) {
  __shared__ u16   Xl[3][TB][XP];                    /* 50688 B triple-buffer */
  __shared__ __align__(16) float s_part[2][TB][SPW]; /* 3072 B, parity       */
  __shared__ float l_part[16];

  const int tid = threadIdx.x;
  const int w   = tid >> 6;           /* wave 0..7: owns ctx cols w*16..+15 */
  const int l   = tid & 63;
  const int l15 = l & 15;
  const int lg  = l >> 4;

  const int blk  = blockIdx.x;
  const int b    = blk >> 4;                          /* / BLK_PER_B */
  const int rowB = (blk & (BLK_PER_B - 1)) * ROWS_PB;
  const float* Xbase = X + ((size_t)b * T_N + rowB) * D_N;

  /* ---- W^T fragments in registers: 8 x bf16x8 = 32 VGPRs ---- */
  bf16x8 bw[8];
  {
    const u16* wp = Wt + (w * 16 + l15) * D_N + lg * 8;
    #pragma unroll
    for (int kk = 0; kk < 8; ++kk) bw[kk] = *(const bf16x8*)(wp + kk * 32);
  }
  const float uc = u[w * 16 + l15];

  /* staging map: thread = (row srow, 16-float segment scol) */
  const int srow = tid >> 4;          /* 0..31 */
  const int scol = (tid & 15) << 4;   /* 0,16,...,240 */
  const float* Xrow = Xbase + (size_t)srow * D_N + scol;

  float4 pf0, pf1, pf2, pf3;          /* prefetch regs (next chunk) */
  pf0 = ((const float4*)Xrow)[0]; pf1 = ((const float4*)Xrow)[1];
  pf2 = ((const float4*)Xrow)[2]; pf3 = ((const float4*)Xrow)[3];

  /* wsum map: thread = (t-pair g, d8 slice) */
  const int g     = tid >> 5;         /* 0..15 -> rows 2g,2g+1 */
  const int slice = tid & 31;         /* d = slice*8 .. +8     */
  float o8[8] = {0,0,0,0,0,0,0,0};
  float l_run = 0.f;

  /* deferred weighted-sum for chunk m (reads s_part[m&1], Xl[m%3]) */
  auto wsum = [&](int m) {
    const int pb = m % 3, sp = m & 1;
    float4 sa0 = *(const float4*)&s_part[sp][2 * g][0];
    float4 sa1 = *(const float4*)&s_part[sp][2 * g][4];
    float4 sb0 = *(const float4*)&s_part[sp][2 * g + 1][0];
    float4 sb1 = *(const float4*)&s_part[sp][2 * g + 1][4];
    float st0 = sa0.x; st0 += sa0.y; st0 += sa0.z; st0 += sa0.w;
    st0 += sa1.x; st0 += sa1.y; st0 += sa1.z; st0 += sa1.w;
    float st1 = sb0.x; st1 += sb0.y; st1 += sb0.z; st1 += sb0.w;
    st1 += sb1.x; st1 += sb1.y; st1 += sb1.z; st1 += sb1.w;
    float p0 = __expf(st0), p1 = __expf(st1);
    if (slice == 0) l_run += p0 + p1;
    u16x8 x0 = *(const u16x8*)&Xl[pb][2 * g][slice * 8];
    u16x8 x1 = *(const u16x8*)&Xl[pb][2 * g + 1][slice * 8];
    #pragma unroll
    for (int j = 0; j < 8; ++j) o8[j] += p0 * bf2f(x0[j]) + p1 * bf2f(x1[j]);
  };

  for (int c = 0; c < CPB; ++c) {
    const int cb = c % 3;

    /* ---- stage chunk c (fp32 regs -> bf16 LDS buf[c%3]) ---- */
    u16x8 s0, s1;
    s0[0]=f2bf(pf0.x); s0[1]=f2bf(pf0.y); s0[2]=f2bf(pf0.z); s0[3]=f2bf(pf0.w);
    s0[4]=f2bf(pf1.x); s0[5]=f2bf(pf1.y); s0[6]=f2bf(pf1.z); s0[7]=f2bf(pf1.w);
    s1[0]=f2bf(pf2.x); s1[1]=f2bf(pf2.y); s1[2]=f2bf(pf2.z); s1[3]=f2bf(pf2.w);
    s1[4]=f2bf(pf3.x); s1[5]=f2bf(pf3.y); s1[6]=f2bf(pf3.z); s1[7]=f2bf(pf3.w);
    *(u16x8*)&Xl[cb][srow][scol]     = s0;
    *(u16x8*)&Xl[cb][srow][scol + 8] = s1;

    /* ---- issue next chunk's global loads (fly across the barrier) ---- */
    if (c + 1 < CPB) {
      const float* sp_ = Xrow + (size_t)(c + 1) * TB * D_N;
      pf0 = ((const float4*)sp_)[0]; pf1 = ((const float4*)sp_)[1];
      pf2 = ((const float4*)sp_)[2]; pf3 = ((const float4*)sp_)[3];
    }

    asm volatile("s_waitcnt lgkmcnt(0)" ::: "memory");
    __builtin_amdgcn_s_barrier();     /* buf[c%3] + s_part[(c-1)&1] ready */
    asm volatile("" ::: "memory");

    /* ---- deferred wsum for chunk c-1 (overlaps MFMA region) ---- */
    if (c >= 1) wsum(c - 1);

    /* ---- scores chunk c: 32 rows x (this wave's 16 ctx cols), K=256 ---- */
    const u16* Xc = &Xl[cb][0][0];
    f32x4 acc0 = {0,0,0,0}, acc1 = {0,0,0,0};
    #pragma unroll
    for (int kk = 0; kk < 8; ++kk) {
      bf16x8 a0 = *(const bf16x8*)(Xc + l15 * XP + kk * 32 + lg * 8);
      bf16x8 a1 = *(const bf16x8*)(Xc + (16 + l15) * XP + kk * 32 + lg * 8);
      acc0 = __builtin_amdgcn_mfma_f32_16x16x32_bf16(a0, bw[kk], acc0, 0, 0, 0);
      acc1 = __builtin_amdgcn_mfma_f32_16x16x32_bf16(a1, bw[kk], acc1, 0, 0, 0);
    }
    /* s-partials: DPP reduce leaves sums in ALL lanes; select by l15 and
       write rows lg*4+l15 with lanes l15<4 -> 2 ds_write_b32 (was 8). */
    {
      float sv0 = rr16_add(uc * fast_tanh(acc0[0]));
      float sv1 = rr16_add(uc * fast_tanh(acc0[1]));
      float sv2 = rr16_add(uc * fast_tanh(acc0[2]));
      float sv3 = rr16_add(uc * fast_tanh(acc0[3]));
      float tv0 = rr16_add(uc * fast_tanh(acc1[0]));
      float tv1 = rr16_add(uc * fast_tanh(acc1[1]));
      float tv2 = rr16_add(uc * fast_tanh(acc1[2]));
      float tv3 = rr16_add(uc * fast_tanh(acc1[3]));
      float selA = (l15 & 2) ? ((l15 & 1) ? sv3 : sv2)
                             : ((l15 & 1) ? sv1 : sv0);
      float selB = (l15 & 2) ? ((l15 & 1) ? tv3 : tv2)
                             : ((l15 & 1) ? tv1 : tv0);
      if (l15 < 4) {
        s_part[c & 1][lg * 4 + l15][w]      = selA;
        s_part[c & 1][16 + lg * 4 + l15][w] = selB;
      }
    }
  }

  /* ---- final deferred wsum (chunk CPB-1) ---- */
  asm volatile("s_waitcnt lgkmcnt(0)" ::: "memory");
  __builtin_amdgcn_s_barrier();
  asm volatile("" ::: "memory");
  wsum(CPB - 1);

  /* ---- block combine: 16 t-groups -> one partial per d ---- */
  asm volatile("s_waitcnt lgkmcnt(0)" ::: "memory");
  __builtin_amdgcn_s_barrier();
  asm volatile("" ::: "memory");
  float* comb = (float*)&Xl[0][0][0];   /* 16 KiB, overlays buffer 0 */
  #pragma unroll
  for (int j = 0; j < 8; ++j) comb[g * 256 + slice * 8 + j] = o8[j];
  if (slice == 0) l_part[g] = l_run;
  asm volatile("s_waitcnt lgkmcnt(0)" ::: "memory");
  __builtin_amdgcn_s_barrier();
  asm volatile("" ::: "memory");
  if (tid < 256) {
    float o = 0.f;
    #pragma unroll
    for (int g2 = 0; g2 < 16; ++g2) o += comb[g2 * 256 + tid];
    blk_o[(size_t)blk * D_N + tid] = o;
  }
  if (tid == 0) {
    float L = 0.f;
    #pragma unroll
    for (int g2 = 0; g2 < 16; ++g2) L += l_part[g2];
    blk_l[blk] = L;
  }
}

/* ---------- kernel 2: combine block-partials per batch ---------- */
__global__ __launch_bounds__(256)
void finalize(const float* __restrict__ blk_o, const float* __restrict__ blk_l,
              float* __restrict__ out) {
  const int b = blockIdx.x, d = threadIdx.x;
  float o = 0.f, L = 0.f;
  for (int i = 0; i < BLK_PER_B; ++i) {
    o += blk_o[(size_t)(b * BLK_PER_B + i) * D_N + d];
    L += blk_l[b * BLK_PER_B + i];
  }
  out[b * D_N + d] = o / L;
}

/* ---------- launch ---------- */
extern "C" void kernel_launch(void* const* d_in, const int* in_sizes, int n_in,
                              void* d_out, int out_size, void* d_ws, size_t ws_size,
                              hipStream_t stream) {
  const float* X = (const float*)d_in[0];
  const float* W = (const float*)d_in[1];
  const float* u = (const float*)d_in[2];
  float* out = (float*)d_out;

  u16*   Wt    = (u16*)d_ws;                                        /* 64 KiB */
  float* blk_o = (float*)((char*)d_ws + 65536);                     /* 512 KiB */
  float* blk_l = (float*)((char*)d_ws + 65536 + (size_t)NBLOCKS * D_N * 4);

  prep_w<<<CTX_N, D_N, 0, stream>>>(W, Wt);
  attn_main<<<NBLOCKS, 512, 0, stream>>>(X, Wt, u, blk_o, blk_l);
  finalize<<<B_N, 256, 0, stream>>>(blk_o, blk_l, out);
}

// Round 15
// 51.835 us; speedup vs baseline: 1.4217x; 1.0748x over previous
//
#include <hip/hip_runtime.h>
#include <hip/hip_bf16.h>
#include <stdint.h>

#define B_N   32
#define T_N   8192
#define D_N   256
#define CTX_N 128
#define TB    32                      /* rows per chunk           */
#define CPB   16                      /* chunks per block         */
#define ROWS_PB (TB*CPB)              /* 512 rows per block       */
#define BLK_PER_B (T_N/ROWS_PB)       /* 16 blocks per batch      */
#define NBLOCKS (B_N*BLK_PER_B)       /* 512 = 2 per CU, all resident */
#define XP    264                     /* bf16 pitch (528 B rows)  */
#define SPW   12                      /* s_part row width (floats), 48B */

typedef unsigned short u16;
typedef unsigned int   u32;
typedef __attribute__((ext_vector_type(8))) short bf16x8;
typedef __attribute__((ext_vector_type(8))) unsigned short u16x8;
typedef __attribute__((ext_vector_type(4))) float f32x4;

__device__ __forceinline__ u16 f2bf(float f) {   /* compiler cast (RNE) */
  __hip_bfloat16 h = __float2bfloat16(f);
  return *reinterpret_cast<u16*>(&h);
}
__device__ __forceinline__ float bf2f(u16 h) {
  return __uint_as_float(((u32)h) << 16);
}
__device__ __forceinline__ float fast_tanh(float x) {
  float e = __expf(2.0f * x);
  return (e - 1.0f) * __builtin_amdgcn_rcpf(e + 1.0f);
}
/* 16-lane rotate-reduce on the VALU (DPP row_ror) — off the DS pipe.
   Leaves the full 16-lane sum in EVERY lane of the group. */
__device__ __forceinline__ float rr16_add(float v) {
  int x;
  x = __builtin_amdgcn_update_dpp(0, __float_as_int(v), 0x128, 0xF, 0xF, true); v += __int_as_float(x);
  x = __builtin_amdgcn_update_dpp(0, __float_as_int(v), 0x124, 0xF, 0xF, true); v += __int_as_float(x);
  x = __builtin_amdgcn_update_dpp(0, __float_as_int(v), 0x122, 0xF, 0xF, true); v += __int_as_float(x);
  x = __builtin_amdgcn_update_dpp(0, __float_as_int(v), 0x121, 0xF, 0xF, true); v += __int_as_float(x);
  return v;
}

/* ---------- kernel 1: fused scores+softmax+wsum ----------
   Round-14 structure (triple-buffer, ONE barrier/chunk, deferred wsum,
   CPB=16 all-resident, packed s_part writes) with W-conversion folded
   into the per-block prologue (prep_w kernel eliminated). */
__global__ __launch_bounds__(512, 4)
void attn_main(const float* __restrict__ X, const float* __restrict__ W,
               const float* __restrict__ u,
               float* __restrict__ blk_o, float* __restrict__ blk_l) {
  __shared__ u16   Xl[3][TB][XP];                    /* 50688 B triple-buffer */
  __shared__ __align__(16) float s_part[2][TB][SPW]; /* 3072 B, parity       */
  __shared__ float l_part[16];

  const int tid = threadIdx.x;
  const int w   = tid >> 6;           /* wave 0..7: owns ctx cols w*16..+15 */
  const int l   = tid & 63;
  const int l15 = l & 15;
  const int lg  = l >> 4;

  const int blk  = blockIdx.x;
  const int b    = blk >> 4;                          /* / BLK_PER_B */
  const int rowB = (blk & (BLK_PER_B - 1)) * ROWS_PB;
  const float* Xbase = X + ((size_t)b * T_N + rowB) * D_N;

  /* staging map: thread = (row srow, 16-float segment scol) */
  const int srow = tid >> 4;          /* 0..31 */
  const int scol = (tid & 15) << 4;   /* 0,16,...,240 */
  const float* Xrow = Xbase + (size_t)srow * D_N + scol;

  /* ---- issue chunk-0 HBM prefetch FIRST (long latency) ---- */
  float4 pf0, pf1, pf2, pf3;
  pf0 = ((const float4*)Xrow)[0]; pf1 = ((const float4*)Xrow)[1];
  pf2 = ((const float4*)Xrow)[2]; pf3 = ((const float4*)Xrow)[3];

  /* ---- W^T fragments gathered from fp32 W (hidden under chunk-0 latency);
     bw[kk][j] = bf16(W[(kk*32+lg*8+j)][w*16+l15]) — identical RNE values
     to the old prep_w path, so output is bit-identical. 32 VGPRs. ---- */
  bf16x8 bw[8];
  {
    const float* wcol = W + (w * 16 + l15);
    #pragma unroll
    for (int kk = 0; kk < 8; ++kk) {
      #pragma unroll
      for (int j = 0; j < 8; ++j)
        bw[kk][j] = (short)f2bf(wcol[(size_t)(kk * 32 + lg * 8 + j) * CTX_N]);
    }
  }
  const float uc = u[w * 16 + l15];

  /* wsum map: thread = (t-pair g, d8 slice) */
  const int g     = tid >> 5;         /* 0..15 -> rows 2g,2g+1 */
  const int slice = tid & 31;         /* d = slice*8 .. +8     */
  float o8[8] = {0,0,0,0,0,0,0,0};
  float l_run = 0.f;

  /* deferred weighted-sum for chunk m (reads s_part[m&1], Xl[m%3]) */
  auto wsum = [&](int m) {
    const int pb = m % 3, sp = m & 1;
    float4 sa0 = *(const float4*)&s_part[sp][2 * g][0];
    float4 sa1 = *(const float4*)&s_part[sp][2 * g][4];
    float4 sb0 = *(const float4*)&s_part[sp][2 * g + 1][0];
    float4 sb1 = *(const float4*)&s_part[sp][2 * g + 1][4];
    float st0 = sa0.x; st0 += sa0.y; st0 += sa0.z; st0 += sa0.w;
    st0 += sa1.x; st0 += sa1.y; st0 += sa1.z; st0 += sa1.w;
    float st1 = sb0.x; st1 += sb0.y; st1 += sb0.z; st1 += sb0.w;
    st1 += sb1.x; st1 += sb1.y; st1 += sb1.z; st1 += sb1.w;
    float p0 = __expf(st0), p1 = __expf(st1);
    if (slice == 0) l_run += p0 + p1;
    u16x8 x0 = *(const u16x8*)&Xl[pb][2 * g][slice * 8];
    u16x8 x1 = *(const u16x8*)&Xl[pb][2 * g + 1][slice * 8];
    #pragma unroll
    for (int j = 0; j < 8; ++j) o8[j] += p0 * bf2f(x0[j]) + p1 * bf2f(x1[j]);
  };

  for (int c = 0; c < CPB; ++c) {
    const int cb = c % 3;

    /* ---- stage chunk c (fp32 regs -> bf16 LDS buf[c%3]) ---- */
    u16x8 s0, s1;
    s0[0]=f2bf(pf0.x); s0[1]=f2bf(pf0.y); s0[2]=f2bf(pf0.z); s0[3]=f2bf(pf0.w);
    s0[4]=f2bf(pf1.x); s0[5]=f2bf(pf1.y); s0[6]=f2bf(pf1.z); s0[7]=f2bf(pf1.w);
    s1[0]=f2bf(pf2.x); s1[1]=f2bf(pf2.y); s1[2]=f2bf(pf2.z); s1[3]=f2bf(pf2.w);
    s1[4]=f2bf(pf3.x); s1[5]=f2bf(pf3.y); s1[6]=f2bf(pf3.z); s1[7]=f2bf(pf3.w);
    *(u16x8*)&Xl[cb][srow][scol]     = s0;
    *(u16x8*)&Xl[cb][srow][scol + 8] = s1;

    /* ---- issue next chunk's global loads (fly across the barrier) ---- */
    if (c + 1 < CPB) {
      const float* sp_ = Xrow + (size_t)(c + 1) * TB * D_N;
      pf0 = ((const float4*)sp_)[0]; pf1 = ((const float4*)sp_)[1];
      pf2 = ((const float4*)sp_)[2]; pf3 = ((const float4*)sp_)[3];
    }

    asm volatile("s_waitcnt lgkmcnt(0)" ::: "memory");
    __builtin_amdgcn_s_barrier();     /* buf[c%3] + s_part[(c-1)&1] ready */
    asm volatile("" ::: "memory");

    /* ---- deferred wsum for chunk c-1 (overlaps MFMA region) ---- */
    if (c >= 1) wsum(c - 1);

    /* ---- scores chunk c: 32 rows x (this wave's 16 ctx cols), K=256 ---- */
    const u16* Xc = &Xl[cb][0][0];
    f32x4 acc0 = {0,0,0,0}, acc1 = {0,0,0,0};
    #pragma unroll
    for (int kk = 0; kk < 8; ++kk) {
      bf16x8 a0 = *(const bf16x8*)(Xc + l15 * XP + kk * 32 + lg * 8);
      bf16x8 a1 = *(const bf16x8*)(Xc + (16 + l15) * XP + kk * 32 + lg * 8);
      acc0 = __builtin_amdgcn_mfma_f32_16x16x32_bf16(a0, bw[kk], acc0, 0, 0, 0);
      acc1 = __builtin_amdgcn_mfma_f32_16x16x32_bf16(a1, bw[kk], acc1, 0, 0, 0);
    }
    /* s-partials: DPP reduce leaves sums in ALL lanes; select by l15 and
       write rows lg*4+l15 with lanes l15<4 -> 2 ds_write_b32 (was 8). */
    {
      float sv0 = rr16_add(uc * fast_tanh(acc0[0]));
      float sv1 = rr16_add(uc * fast_tanh(acc0[1]));
      float sv2 = rr16_add(uc * fast_tanh(acc0[2]));
      float sv3 = rr16_add(uc * fast_tanh(acc0[3]));
      float tv0 = rr16_add(uc * fast_tanh(acc1[0]));
      float tv1 = rr16_add(uc * fast_tanh(acc1[1]));
      float tv2 = rr16_add(uc * fast_tanh(acc1[2]));
      float tv3 = rr16_add(uc * fast_tanh(acc1[3]));
      float selA = (l15 & 2) ? ((l15 & 1) ? sv3 : sv2)
                             : ((l15 & 1) ? sv1 : sv0);
      float selB = (l15 & 2) ? ((l15 & 1) ? tv3 : tv2)
                             : ((l15 & 1) ? tv1 : tv0);
      if (l15 < 4) {
        s_part[c & 1][lg * 4 + l15][w]      = selA;
        s_part[c & 1][16 + lg * 4 + l15][w] = selB;
      }
    }
  }

  /* ---- final deferred wsum (chunk CPB-1) ---- */
  asm volatile("s_waitcnt lgkmcnt(0)" ::: "memory");
  __builtin_amdgcn_s_barrier();
  asm volatile("" ::: "memory");
  wsum(CPB - 1);

  /* ---- block combine: 16 t-groups -> one partial per d ---- */
  asm volatile("s_waitcnt lgkmcnt(0)" ::: "memory");
  __builtin_amdgcn_s_barrier();
  asm volatile("" ::: "memory");
  float* comb = (float*)&Xl[0][0][0];   /* 16 KiB, overlays buffer 0 */
  #pragma unroll
  for (int j = 0; j < 8; ++j) comb[g * 256 + slice * 8 + j] = o8[j];
  if (slice == 0) l_part[g] = l_run;
  asm volatile("s_waitcnt lgkmcnt(0)" ::: "memory");
  __builtin_amdgcn_s_barrier();
  asm volatile("" ::: "memory");
  if (tid < 256) {
    float o = 0.f;
    #pragma unroll
    for (int g2 = 0; g2 < 16; ++g2) o += comb[g2 * 256 + tid];
    blk_o[(size_t)blk * D_N + tid] = o;
  }
  if (tid == 0) {
    float L = 0.f;
    #pragma unroll
    for (int g2 = 0; g2 < 16; ++g2) L += l_part[g2];
    blk_l[blk] = L;
  }
}

/* ---------- kernel 2: combine block-partials per batch ---------- */
__global__ __launch_bounds__(256)
void finalize(const float* __restrict__ blk_o, const float* __restrict__ blk_l,
              float* __restrict__ out) {
  const int b = blockIdx.x, d = threadIdx.x;
  float o = 0.f, L = 0.f;
  for (int i = 0; i < BLK_PER_B; ++i) {
    o += blk_o[(size_t)(b * BLK_PER_B + i) * D_N + d];
    L += blk_l[b * BLK_PER_B + i];
  }
  out[b * D_N + d] = o / L;
}

/* ---------- launch ---------- */
extern "C" void kernel_launch(void* const* d_in, const int* in_sizes, int n_in,
                              void* d_out, int out_size, void* d_ws, size_t ws_size,
                              hipStream_t stream) {
  const float* X = (const float*)d_in[0];
  const float* W = (const float*)d_in[1];
  const float* u = (const float*)d_in[2];
  float* out = (float*)d_out;

  float* blk_o = (float*)d_ws;                                      /* 512 KiB */
  float* blk_l = (float*)((char*)d_ws + (size_t)NBLOCKS * D_N * 4);

  attn_main<<<NBLOCKS, 512, 0, stream>>>(X, W, u, blk_o, blk_l);
  finalize<<<B_N, 256, 0, stream>>>(blk_o, blk_l, out);
}